// Round 7
// baseline (398.392 us; speedup 1.0000x reference)
//
#include <hip/hip_runtime.h>
#include <hip/hip_bf16.h>
#include <math.h>

#define M_TOT 4096
#define K_TOT 1024
#define V_TOT 32000

typedef short short8 __attribute__((ext_vector_type(8)));
typedef float f32x4 __attribute__((ext_vector_type(4)));

__device__ __forceinline__ void gload_lds16(const void* g, void* l) {
  __builtin_amdgcn_global_load_lds(
      (const __attribute__((address_space(1))) void*)g,
      (__attribute__((address_space(3))) void*)l, 16, 0, 0);
}

__device__ __forceinline__ unsigned short f2bf(float f) {
  unsigned int u = __builtin_bit_cast(unsigned int, f);
  unsigned int lsb = (u >> 16) & 1u;
  u += 0x7fffu + lsb;
  return (unsigned short)(u >> 16);
}

__device__ __forceinline__ float sani(float v) {
  return (v != v) ? 0.0f : fminf(fmaxf(v, -1e4f), 1e4f);
}

__global__ void prep_h(const float* __restrict__ h, unsigned short* __restrict__ hbf,
                       float* __restrict__ h0) {
  int m = blockIdx.x;
  int t = threadIdx.x;
  const float* row = h + (long)m * (K_TOT + 1);
  if (t == 0) h0[m] = sani(row[0]);
  unsigned short* dst = hbf + (long)m * K_TOT;
#pragma unroll
  for (int j = 0; j < 4; ++j) {
    int idx = t * 4 + j;
    dst[idx] = f2bf(sani(row[1 + idx]));
  }
}

__global__ void prep_w(const float* __restrict__ w, unsigned short* __restrict__ wbf,
                       float* __restrict__ wtime) {
  __shared__ float red[4];
  __shared__ float r_sh;
  int v = blockIdx.x;
  int t = threadIdx.x;
  const float* row = w + (long)v * K_TOT;
  float4 x = *(const float4*)(row + t * 4);
  float s = x.x * x.x + x.y * x.y + x.z * x.z + x.w * x.w;
#pragma unroll
  for (int off = 32; off > 0; off >>= 1) s += __shfl_down(s, off);
  int lane = t & 63, wv = t >> 6;
  if (lane == 0) red[wv] = s;
  __syncthreads();
  if (t == 0) {
    float tot = red[0] + red[1] + red[2] + red[3];
    float norm = sqrtf(tot);
    float r = (norm > 1e-7f) ? (sinhf(norm) / fmaxf(norm, 1e-7f)) : 1.0f;
    r_sh = r;
    wtime[v] = coshf(norm);
  }
  __syncthreads();
  float r = r_sh;
  ushort4 pack;
  pack.x = f2bf(r * x.x);
  pack.y = f2bf(r * x.y);
  pack.z = f2bf(r * x.z);
  pack.w = f2bf(r * x.w);
  *(ushort4*)(wbf + (long)v * K_TOT + t * 4) = pack;
}

// ------- persistent-block 256x256 GEMM: 250 blocks x 8 m-tiles, fixed v ----
// Per block: v-panel fixed (b>>1), m-tiles (b&1)*8 + it for it in [0,8).
// Flat staging rotation over g = it*32+kt in [0,256): triple-buffer
// (buf = g%3) never drains across tile boundaries. Round-6 K-iter body kept.
// LDS XOR swizzle (verified SQ_LDS_BANK_CONFLICT==0): slot chunk c holds
// global k-chunk c ^ ((row>>1)&3); source pre-swizzled cc=(t&3)^((t>>3)&3);
// read chunk = fq ^ ((fr>>1)&3). (rule #21 both-sides)
// Operand swap: acc[im][iv] = mfma(bf[iv], af[im], .) puts v on the reg axis
// (fq*4+j) and m on the lane axis (fr) -> 4 acc regs = 4 consecutive v ->
// float4 stores (32/thread, fits vmcnt windows; plain stores so L2 merges
// 64B halves into full lines - round-6 nt stores showed 1.35x write amp).
// Graded wait: first post-epilogue boundary uses vmcnt(44) = 32 stores +
// 8 h0 loads + 4 newest staging loads (in-order retirement => the needed
// staging batch is proven landed without forcing store drain).
// Registers: acc 128 + frags 48 + misc ~60 <= 256 -> 2 waves/SIMD (the
// (512,2) bound makes the allocator honor this; (512,4) would force 64 and
// spill - round-4 disaster).
#define BAR __builtin_amdgcn_s_barrier()
#define VM4 asm volatile("s_waitcnt vmcnt(4)" ::: "memory")
#define VM44 asm volatile("s_waitcnt vmcnt(44)" ::: "memory")
#define RD8(off) (*(const short8*)(smem + (off)))

__global__ __launch_bounds__(512, 2) void gemm_geo(
    const unsigned short* __restrict__ hbf, const unsigned short* __restrict__ wbf,
    const float* __restrict__ h0, const float* __restrict__ wtime,
    const float* __restrict__ ls, float* __restrict__ out) {
  __shared__ __align__(16) char smem[98304];

  const int t = threadIdx.x;
  const int wave = t >> 6, lane = t & 63;
  const int fr = lane & 15, fq = lane >> 4;
  const int wm = wave >> 2, wn = wave & 3;  // 2 (M) x 4 (N) wave grid

  const int b = blockIdx.x;
  const int col0 = (b >> 1) * 256;  // fixed v-panel
  const int mbase = (b & 1) * 8;    // m-tile range [mbase, mbase+8)

  // ds_read lane bases (bytes), + buf*32768 + frag*1024
  const int sw = (fq ^ ((fr >> 1) & 3)) * 16;
  const int a_rd = (wm * 128 + fr) * 64 + sw;
  const int b_rd = 16384 + (wn * 64 + fr) * 64 + sw;

  const int cc = (t & 3) ^ ((t >> 3) & 3);
  const unsigned short* pA0 =
      hbf + ((long)(mbase * 256) + (t >> 2)) * K_TOT + cc * 8;
  const unsigned short* pB = wbf + ((long)col0 + (t >> 2)) * K_TOT + cc * 8;
  const int dst_w = wave * 1024;  // wave-uniform; HW adds lane*16

  auto STAGE = [&](int g, int sb) {
    const unsigned short* a = pA0 + (long)(g >> 5) * (256 * K_TOT) + (g & 31) * 32;
    const unsigned short* bb = pB + (g & 31) * 32;
#pragma unroll
    for (int h = 0; h < 2; ++h) {
      gload_lds16(a + (long)h * 131072, smem + sb * 32768 + h * 8192 + dst_w);
      gload_lds16(bb + (long)h * 131072,
                  smem + sb * 32768 + 16384 + h * 8192 + dst_w);
    }
  };

  // per-block constants (issued before the staging stream)
  float ntau = -fminf(fmaxf(ls[0], 0.01f), 2.5f);
  const float LN2 = 0.69314718055994531f;
  float4 wt4[4];
#pragma unroll
  for (int iv = 0; iv < 4; ++iv)
    wt4[iv] = *(const float4*)&wtime[col0 + wn * 64 + iv * 16 + fq * 4];

  f32x4 acc[8][4];
#pragma unroll
  for (int i = 0; i < 8; ++i)
#pragma unroll
    for (int j = 0; j < 4; ++j) acc[i][j] = (f32x4)(0.0f);

  // prologue: flat tiles 0,1 -> bufs 0,1
  STAGE(0, 0);
  STAGE(1, 1);
  VM4;
  BAR;

#pragma unroll 1
  for (int it = 0; it < 8; ++it) {
    const int row0 = (mbase + it) * 256;
    float h0v[8];
#pragma unroll
    for (int im = 0; im < 8; ++im)
      h0v[im] = h0[row0 + wm * 128 + im * 16 + fr];

#pragma unroll 1
    for (int kt = 0; kt < 32; ++kt) {
      int g = it * 32 + kt;
      int sg = (g + 2 <= 255) ? g + 2 : 255;  // clamped redundant tail stage
      int sb = (g + 2) % 3;
      STAGE(sg, sb);

      int cb = g % 3;
      short8 af[8], bf[4];
      int abase = a_rd + cb * 32768;
      int bbase = b_rd + cb * 32768;
#pragma unroll
      for (int im = 0; im < 8; ++im) af[im] = RD8(abase + im * 1024);
#pragma unroll
      for (int iv = 0; iv < 4; ++iv) bf[iv] = RD8(bbase + iv * 1024);

      __builtin_amdgcn_s_setprio(1);
#pragma unroll
      for (int im = 0; im < 8; ++im)
#pragma unroll
        for (int iv = 0; iv < 4; ++iv)
          acc[im][iv] = __builtin_amdgcn_mfma_f32_16x16x32_bf16(
              bf[iv], af[im], acc[im][iv], 0, 0, 0);
      __builtin_amdgcn_s_setprio(0);

      // boundary: prove staging batch (g+1) landed. After an epilogue the
      // window also holds 32 stores + 8 h0 loads -> 44; else 4.
      if (kt == 0 && it > 0) {
        VM44;
      } else {
        VM4;
      }
      BAR;
    }

    // epilogue tile it: x = h0*w_time - dot; d2 = safe_acosh(x)^2; -tau*d2
#pragma unroll
    for (int im = 0; im < 8; ++im) {
      float hh = h0v[im];
      float* orow =
          out + (long)(row0 + wm * 128 + im * 16 + fr) * V_TOT + col0 + wn * 64;
#pragma unroll
      for (int iv = 0; iv < 4; ++iv) {
        f32x4 r;
#pragma unroll
        for (int j = 0; j < 4; ++j) {
          float x = fmaf(hh, wt4[iv][j == 0 ? 0 : j == 1 ? 1 : j == 2 ? 2 : 3],
                         -acc[im][iv][j]);
          float xm1 = fmaxf(x - 1.0f, 0.0f);
          float arg = fmaxf(fmaf(x, x, -1.0f), 0.0f);
          float lg2 = __builtin_amdgcn_logf(x + __builtin_amdgcn_sqrtf(arg));
          float dex = LN2 * lg2;
          float d2_exact = dex * dex;
          float ts = fmaf(xm1, -1.0f / 12.0f, 1.0f);
          float d2_tay = 2.0f * xm1 * ts * ts;
          float d2 = (xm1 < 1e-3f) ? d2_tay : d2_exact;
          r[j] = ntau * d2;
        }
        *(f32x4*)(orow + iv * 16 + fq * 4) = r;
        acc[im][iv] = (f32x4)(0.0f);  // reset for next tile (after store reads)
      }
    }
  }
}

extern "C" void kernel_launch(void* const* d_in, const int* in_sizes, int n_in,
                              void* d_out, int out_size, void* d_ws, size_t ws_size,
                              hipStream_t stream) {
  const float* h = (const float*)d_in[0];   // [2,2048,1025]
  const float* w = (const float*)d_in[1];   // [32000,1024]
  const float* ls = (const float*)d_in[2];  // scalar
  float* out = (float*)d_out;               // [2,2048,32000] fp32

  char* ws = (char*)d_ws;
  unsigned short* wbf = (unsigned short*)ws;                  // 65,536,000 B
  unsigned short* hbf = (unsigned short*)(ws + 65536000);     // 8,388,608 B
  float* wtime = (float*)(ws + 65536000 + 8388608);           // 128,000 B
  float* h0 = (float*)(ws + 65536000 + 8388608 + 128000);     // 16,384 B

  prep_h<<<M_TOT, 256, 0, stream>>>(h, hbf, h0);
  prep_w<<<V_TOT, 256, 0, stream>>>(w, wbf, wtime);
  gemm_geo<<<250, 512, 0, stream>>>(hbf, wbf, h0, wtime, ls, out);
}

// Round 8
// 398.131 us; speedup vs baseline: 1.0007x; 1.0007x over previous
//
#include <hip/hip_runtime.h>
#include <hip/hip_bf16.h>
#include <math.h>

#define M_TOT 4096
#define K_TOT 1024
#define V_TOT 32000

typedef short short8 __attribute__((ext_vector_type(8)));
typedef float f32x4 __attribute__((ext_vector_type(4)));

__device__ __forceinline__ void gload_lds16(const void* g, void* l) {
  __builtin_amdgcn_global_load_lds(
      (const __attribute__((address_space(1))) void*)g,
      (__attribute__((address_space(3))) void*)l, 16, 0, 0);
}

__device__ __forceinline__ unsigned short f2bf(float f) {
  unsigned int u = __builtin_bit_cast(unsigned int, f);
  unsigned int lsb = (u >> 16) & 1u;
  u += 0x7fffu + lsb;
  return (unsigned short)(u >> 16);
}

__device__ __forceinline__ float sani(float v) {
  return (v != v) ? 0.0f : fminf(fmaxf(v, -1e4f), 1e4f);
}

__global__ void prep_h(const float* __restrict__ h, unsigned short* __restrict__ hbf,
                       float* __restrict__ h0) {
  int m = blockIdx.x;
  int t = threadIdx.x;
  const float* row = h + (long)m * (K_TOT + 1);
  if (t == 0) h0[m] = sani(row[0]);
  unsigned short* dst = hbf + (long)m * K_TOT;
#pragma unroll
  for (int j = 0; j < 4; ++j) {
    int idx = t * 4 + j;
    dst[idx] = f2bf(sani(row[1 + idx]));
  }
}

__global__ void prep_w(const float* __restrict__ w, unsigned short* __restrict__ wbf,
                       float* __restrict__ wtime) {
  __shared__ float red[4];
  __shared__ float r_sh;
  int v = blockIdx.x;
  int t = threadIdx.x;
  const float* row = w + (long)v * K_TOT;
  float4 x = *(const float4*)(row + t * 4);
  float s = x.x * x.x + x.y * x.y + x.z * x.z + x.w * x.w;
#pragma unroll
  for (int off = 32; off > 0; off >>= 1) s += __shfl_down(s, off);
  int lane = t & 63, wv = t >> 6;
  if (lane == 0) red[wv] = s;
  __syncthreads();
  if (t == 0) {
    float tot = red[0] + red[1] + red[2] + red[3];
    float norm = sqrtf(tot);
    float r = (norm > 1e-7f) ? (sinhf(norm) / fmaxf(norm, 1e-7f)) : 1.0f;
    r_sh = r;
    wtime[v] = coshf(norm);
  }
  __syncthreads();
  float r = r_sh;
  ushort4 pack;
  pack.x = f2bf(r * x.x);
  pack.y = f2bf(r * x.y);
  pack.z = f2bf(r * x.z);
  pack.w = f2bf(r * x.w);
  *(ushort4*)(wbf + (long)v * K_TOT + t * 4) = pack;
}

// ---- 256x256 tile, BK=32, triple-buffer + 2-phase interleaved GEMM --------
// Proven pieces kept: XCD-grouped grid (FETCH 309MB, r5/r6), zero-conflict
// XOR swizzle (r4-r7), operand-swapped MFMA + plain float4 stores (WRITE
// 513MB, r7), (512,2) launch bounds (r4: (512,4) -> 64-VGPR cap -> acc spill
// -> 13.9GB HBM).
// New: per K-tile kt (compute buf kt%3, stage tile kt+2 -> buf (kt+2)%3):
//   Phase A: ds_read 4B+4A frags; stage A-halves of kt+2; 16 MFMA (m0-3); BAR
//   Phase B: ds_read 4A frags (B reused in regs); stage B-halves; 16 MFMA
//            (m4-7); vmcnt(4) (kt+1 proven landed, kt+2's 4 stay in flight);
//            BAR
// 2 barriers + 1 counted vmcnt per K-tile; staging lead = 2 K-tiles (~2.8k
// cyc >> 900-cyc HBM latency). Stage-vs-read safety: writes hit buf
// (kt+2)%3, reads hit kt%3 (disjoint); the overwritten tile kt-1's last
// reads completed before the end-of-(kt-1) barrier, stage issues after it.
#define BAR __builtin_amdgcn_s_barrier()
#define FENCE asm volatile("" ::: "memory")
#define VM4 asm volatile("s_waitcnt vmcnt(4)" ::: "memory")
#define RD8(off) (*(const short8*)(smem + (off)))

__global__ __launch_bounds__(512, 2) void gemm_geo(
    const unsigned short* __restrict__ hbf, const unsigned short* __restrict__ wbf,
    const float* __restrict__ h0, const float* __restrict__ wtime,
    const float* __restrict__ ls, float* __restrict__ out) {
  __shared__ __align__(16) char smem[98304];

  const int t = threadIdx.x;
  const int wave = t >> 6, lane = t & 63;
  const int fr = lane & 15, fq = lane >> 4;
  const int wm = wave >> 2, wn = wave & 3;  // 2 (M) x 4 (N) wave grid

  // XCD-grouped bijective swizzle: 2000 blocks, 250/XCD; 16 consecutive
  // blocks per XCD share one 512KB B-panel concurrently (spatial L2 reuse).
  const int bid = blockIdx.x;
  const int swz = (bid & 7) * 250 + (bid >> 3);
  const int tile_v = swz >> 4;
  const int tile_m = swz & 15;
  const int row0 = tile_m * 256;
  const int col0 = tile_v * 256;

  // ds_read lane bases (bytes), + buf*32768 + frag*1024
  const int sw = (fq ^ ((fr >> 1) & 3)) * 16;
  const int a_rd = (wm * 128 + fr) * 64 + sw;
  const int b_rd = 16384 + (wn * 64 + fr) * 64 + sw;

  // staging: thread t -> row t>>2 (+128 for h=1), slot chunk t&3; source
  // k-chunk pre-swizzled cc = (t&3)^((t>>3)&3) (slot c holds global chunk
  // c ^ ((row>>1)&3); read side applies same XOR -> involution, rule #21)
  const int cc = (t & 3) ^ ((t >> 3) & 3);
  const unsigned short* pA = hbf + ((long)row0 + (t >> 2)) * K_TOT + cc * 8;
  const unsigned short* pB = wbf + ((long)col0 + (t >> 2)) * K_TOT + cc * 8;
  const int dst_w = wave * 1024;  // wave-uniform; HW adds lane*16

  auto STAGE_A = [&](int g, int sb) {
#pragma unroll
    for (int h = 0; h < 2; ++h)
      gload_lds16(pA + (long)h * 131072 + g * 32,
                  smem + sb * 32768 + h * 8192 + dst_w);
  };
  auto STAGE_B = [&](int g, int sb) {
#pragma unroll
    for (int h = 0; h < 2; ++h)
      gload_lds16(pB + (long)h * 131072 + g * 32,
                  smem + sb * 32768 + 16384 + h * 8192 + dst_w);
  };

  f32x4 acc[8][4];
#pragma unroll
  for (int i = 0; i < 8; ++i)
#pragma unroll
    for (int j = 0; j < 4; ++j) acc[i][j] = (f32x4)(0.0f);

  // prologue: tiles 0,1 -> bufs 0,1 (A then B each; 8 loads). vmcnt(4):
  // tile0's 4 (oldest, in-order retire) proven landed; tile1 may fly.
  STAGE_A(0, 0); STAGE_B(0, 0);
  STAGE_A(1, 1); STAGE_B(1, 1);
  VM4;
  BAR;

#pragma unroll 1
  for (int kt = 0; kt < 32; ++kt) {
    const int cb = kt % 3;
    const int sg = (kt + 2 < 32) ? kt + 2 : 31;  // clamped redundant tail
    const int sb = (kt + 2) % 3;
    const int abase = a_rd + cb * 32768;
    const int bbase = b_rd + cb * 32768;

    short8 af[4], bf[4];
    // ---- Phase A: B frags + A frags m0-3; stage kt+2 A; MFMA m0-3 ----
#pragma unroll
    for (int iv = 0; iv < 4; ++iv) bf[iv] = RD8(bbase + iv * 1024);
#pragma unroll
    for (int i = 0; i < 4; ++i) af[i] = RD8(abase + i * 1024);
    STAGE_A(sg, sb);
    __builtin_amdgcn_s_setprio(1);
#pragma unroll
    for (int i = 0; i < 4; ++i)
#pragma unroll
      for (int iv = 0; iv < 4; ++iv)
        acc[i][iv] = __builtin_amdgcn_mfma_f32_16x16x32_bf16(
            bf[iv], af[i], acc[i][iv], 0, 0, 0);
    __builtin_amdgcn_s_setprio(0);
    FENCE;
    BAR;
    __builtin_amdgcn_sched_barrier(0);

    // ---- Phase B: A frags m4-7 (B reused); stage kt+2 B; MFMA m4-7 ----
#pragma unroll
    for (int i = 0; i < 4; ++i) af[i] = RD8(abase + (4 + i) * 1024);
    STAGE_B(sg, sb);
    __builtin_amdgcn_s_setprio(1);
#pragma unroll
    for (int i = 0; i < 4; ++i)
#pragma unroll
      for (int iv = 0; iv < 4; ++iv)
        acc[4 + i][iv] = __builtin_amdgcn_mfma_f32_16x16x32_bf16(
            bf[iv], af[i], acc[4 + i][iv], 0, 0, 0);
    __builtin_amdgcn_s_setprio(0);
    VM4;  // kt+1 fully landed (its 4 loads are 4-back); kt+2's 4 in flight
    BAR;
  }

  // fused epilogue: x = h0*w_time - dot; d2 = safe_acosh(x)^2; out = -tau*d2
  // (operand swap put v on the acc reg axis -> float4 stores, m on lanes)
  const float ntau = -fminf(fmaxf(ls[0], 0.01f), 2.5f);
  const float LN2 = 0.69314718055994531f;
  f32x4 wt4[4];
#pragma unroll
  for (int iv = 0; iv < 4; ++iv)
    wt4[iv] = *(const f32x4*)&wtime[col0 + wn * 64 + iv * 16 + fq * 4];
#pragma unroll
  for (int im = 0; im < 8; ++im) {
    const float hh = h0[row0 + wm * 128 + im * 16 + fr];
    float* orow =
        out + (long)(row0 + wm * 128 + im * 16 + fr) * V_TOT + col0 + wn * 64;
#pragma unroll
    for (int iv = 0; iv < 4; ++iv) {
      f32x4 r;
#pragma unroll
      for (int j = 0; j < 4; ++j) {
        float x = fmaf(hh, wt4[iv][j], -acc[im][iv][j]);
        float xm1 = fmaxf(x - 1.0f, 0.0f);
        float arg = fmaxf(fmaf(x, x, -1.0f), 0.0f);
        float lg2 = __builtin_amdgcn_logf(x + __builtin_amdgcn_sqrtf(arg));
        float dex = LN2 * lg2;
        float d2_exact = dex * dex;
        float ts = fmaf(xm1, -1.0f / 12.0f, 1.0f);
        float d2_tay = 2.0f * xm1 * ts * ts;
        float d2 = (xm1 < 1e-3f) ? d2_tay : d2_exact;
        r[j] = ntau * d2;
      }
      *(f32x4*)(orow + iv * 16 + fq * 4) = r;
    }
  }
}

extern "C" void kernel_launch(void* const* d_in, const int* in_sizes, int n_in,
                              void* d_out, int out_size, void* d_ws, size_t ws_size,
                              hipStream_t stream) {
  const float* h = (const float*)d_in[0];   // [2,2048,1025]
  const float* w = (const float*)d_in[1];   // [32000,1024]
  const float* ls = (const float*)d_in[2];  // scalar
  float* out = (float*)d_out;               // [2,2048,32000] fp32

  char* ws = (char*)d_ws;
  unsigned short* wbf = (unsigned short*)ws;                  // 65,536,000 B
  unsigned short* hbf = (unsigned short*)(ws + 65536000);     // 8,388,608 B
  float* wtime = (float*)(ws + 65536000 + 8388608);           // 128,000 B
  float* h0 = (float*)(ws + 65536000 + 8388608 + 128000);     // 16,384 B

  prep_h<<<M_TOT, 256, 0, stream>>>(h, hbf, h0);
  prep_w<<<V_TOT, 256, 0, stream>>>(w, wbf, wtime);
  gemm_geo<<<2000, 512, 0, stream>>>(hbf, wbf, h0, wtime, ls, out);
}